// Round 1
// baseline (824.538 us; speedup 1.0000x reference)
//
#include <hip/hip_runtime.h>
#include <hip/hip_bf16.h>

#define NCELLS 256
#define DIM    512
#define NTOK   131072

typedef __attribute__((ext_vector_type(8))) short  bf16x8;
typedef __attribute__((ext_vector_type(4))) float  f32x4;

static __device__ __forceinline__ unsigned short f2bf(float f) {
    union { float f; unsigned u; } v; v.f = f;
    unsigned r = v.u + 0x7fffu + ((v.u >> 16) & 1u);
    return (unsigned short)(r >> 16);
}

static __device__ __forceinline__ bf16x8 cvt8(f32x4 a, f32x4 b) {
    bf16x8 r;
    r[0] = (short)f2bf(a[0]); r[1] = (short)f2bf(a[1]);
    r[2] = (short)f2bf(a[2]); r[3] = (short)f2bf(a[3]);
    r[4] = (short)f2bf(b[0]); r[5] = (short)f2bf(b[1]);
    r[6] = (short)f2bf(b[2]); r[7] = (short)f2bf(b[3]);
    return r;
}

// ---------------- prep: bf16 copies + norms + gate + 1/T ----------------
__global__ void __launch_bounds__(256) prep_kernel(
        const float* __restrict__ proto, const float* __restrict__ grid,
        const float* __restrict__ temp_raw, const float* __restrict__ gate_logits,
        unsigned short* __restrict__ pcomb,   // [512][512] rows 0..255 proto, 256..511 grid
        unsigned short* __restrict__ protoT,  // [512][256] protoT[d][c] = proto[c][d]
        float* __restrict__ pp, float* __restrict__ gg,
        float* __restrict__ gate, float* __restrict__ invT)
{
    const int c = blockIdx.x;   // cell 0..255
    const int t = threadIdx.x;  // 0..255
    float sp = 0.f, sg = 0.f;
    for (int i = t; i < DIM; i += 256) {
        float pv = proto[c * DIM + i];
        float gv = grid[c * DIM + i];
        pcomb[c * DIM + i]            = f2bf(pv);
        pcomb[(NCELLS + c) * DIM + i] = f2bf(gv);
        protoT[i * NCELLS + c]        = f2bf(pv);
        sp += pv * pv; sg += gv * gv;
    }
    for (int m = 1; m < 64; m <<= 1) { sp += __shfl_xor(sp, m); sg += __shfl_xor(sg, m); }
    __shared__ float redp[4], redg[4];
    const int wv = t >> 6;
    if ((t & 63) == 0) { redp[wv] = sp; redg[wv] = sg; }
    __syncthreads();
    if (t == 0) {
        pp[c] = redp[0] + redp[1] + redp[2] + redp[3];
        gg[c] = redg[0] + redg[1] + redg[2] + redg[3];
        gate[c] = 1.f / (1.f + expf(-gate_logits[c]));
        if (c == 0) {
            float T = (1.f / (1.f + expf(-temp_raw[0]))) * (1.f - 0.001f) + 0.001f;
            invT[0] = 1.f / T;
        }
    }
}

// ---------------- main fused kernel ----------------
// 4 waves/block, 16 tokens/wave, 64 tokens/block. 2048 blocks.
__global__ void __launch_bounds__(256) som_main(
        const float* __restrict__ x,
        const unsigned short* __restrict__ pcomb,
        const unsigned short* __restrict__ protoT,
        const float* __restrict__ pp, const float* __restrict__ gg,
        const float* __restrict__ gate, const float* __restrict__ invTp,
        float* __restrict__ out_blend, float* __restrict__ out_w)
{
    const int lane = threadIdx.x & 63;
    const int wv   = threadIdx.x >> 6;
    const int tb   = blockIdx.x * 64 + wv * 16;  // wave's token base
    const int r    = lane & 15;                  // A-row / B-col / C-col index
    const int g    = lane >> 4;                  // lane group 0..3
    const int k8   = g * 8;                      // K sub-offset within 32

    __shared__ unsigned short lds_w[4][16][264]; // +8 pad: 2-way bank alias only (free)

    const float invT = invTp[0];

    // ---- Phase 1: x tile -> A fragments (bf16) + |x|^2 (fp32) ----
    bf16x8 a1[16];
    float xx_part = 0.f;
    const float* xrow = x + (size_t)(tb + r) * DIM;
    #pragma unroll
    for (int ks = 0; ks < 16; ++ks) {
        const f32x4* p0 = (const f32x4*)(xrow + ks * 32 + k8);
        f32x4 u0 = p0[0], u1 = p0[1];
        #pragma unroll
        for (int i = 0; i < 4; ++i) xx_part += u0[i] * u0[i] + u1[i] * u1[i];
        a1[ks] = cvt8(u0, u1);
    }
    // reduce |x|^2 across the 4 lane groups (same r = same token)
    xx_part += __shfl_xor(xx_part, 16);
    xx_part += __shfl_xor(xx_part, 32);
    // redistribute to C/D token mapping: token = g*4 + j
    float xt[4];
    #pragma unroll
    for (int j = 0; j < 4; ++j) xt[j] = __shfl(xx_part, g * 4 + j);

    // ---- Phase 2: dots vs all 256 cells (proto & grid), z = -d_total/T ----
    f32x4 zfr[16];
    float gv[16];
    float m4[4] = {-1e30f, -1e30f, -1e30f, -1e30f};
    #pragma unroll
    for (int ct = 0; ct < 16; ++ct) {
        f32x4 accP = {0.f, 0.f, 0.f, 0.f};
        f32x4 accG = {0.f, 0.f, 0.f, 0.f};
        const unsigned short* bPr = pcomb + (size_t)(ct * 16 + r) * DIM + k8;
        const unsigned short* bGr = pcomb + (size_t)(NCELLS + ct * 16 + r) * DIM + k8;
        #pragma unroll
        for (int ks = 0; ks < 16; ++ks) {
            bf16x8 bP = *(const bf16x8*)(bPr + ks * 32);
            bf16x8 bG = *(const bf16x8*)(bGr + ks * 32);
            accP = __builtin_amdgcn_mfma_f32_16x16x32_bf16(a1[ks], bP, accP, 0, 0, 0);
            accG = __builtin_amdgcn_mfma_f32_16x16x32_bf16(a1[ks], bG, accG, 0, 0, 0);
        }
        const int cell = ct * 16 + r;
        const float ppc = pp[cell], ggc = gg[cell];
        gv[ct] = gate[cell];
        f32x4 z;
        #pragma unroll
        for (int j = 0; j < 4; ++j) {
            float dp = sqrtf(fmaxf(xt[j] + ppc - 2.f * accP[j], 0.f));
            float dg = sqrtf(fmaxf(xt[j] + ggc - 2.f * accG[j], 0.f));
            z[j] = -(dp + dg) * invT;
            m4[j] = fmaxf(m4[j], z[j]);
        }
        zfr[ct] = z;
    }

    // ---- Phase 3: softmax over 256 cells (cross-lane within 16-lane group) ----
    #pragma unroll
    for (int j = 0; j < 4; ++j) {
        float m = m4[j];
        m = fmaxf(m, __shfl_xor(m, 1));
        m = fmaxf(m, __shfl_xor(m, 2));
        m = fmaxf(m, __shfl_xor(m, 4));
        m = fmaxf(m, __shfl_xor(m, 8));
        m4[j] = m;
    }
    float s1[4] = {0.f, 0.f, 0.f, 0.f};
    float s2[4] = {0.f, 0.f, 0.f, 0.f};
    #pragma unroll
    for (int ct = 0; ct < 16; ++ct) {
        f32x4 z = zfr[ct];
        #pragma unroll
        for (int j = 0; j < 4; ++j) {
            float p = __expf(z[j] - m4[j]);
            s1[j] += p;
            float q = p * gv[ct];
            s2[j] += q;
            z[j] = q;
        }
        zfr[ct] = z;
    }
    float rden[4];
    #pragma unroll
    for (int j = 0; j < 4; ++j) {
        float a = s1[j], b = s2[j];
        a += __shfl_xor(a, 1); b += __shfl_xor(b, 1);
        a += __shfl_xor(a, 2); b += __shfl_xor(b, 2);
        a += __shfl_xor(a, 4); b += __shfl_xor(b, 4);
        a += __shfl_xor(a, 8); b += __shfl_xor(b, 8);
        rden[j] = 1.f / (b + 1e-8f * a);
    }

    // ---- Phase 4: write weights (fp32) + stash bf16 W into LDS ----
    float* wout = out_w + (size_t)tb * NCELLS;
    #pragma unroll
    for (int ct = 0; ct < 16; ++ct) {
        #pragma unroll
        for (int j = 0; j < 4; ++j) {
            float w = zfr[ct][j] * rden[j];
            const int tok = g * 4 + j;
            wout[(size_t)tok * NCELLS + ct * 16 + r] = w;
            float nb = __shfl_xor(w, 1);  // neighbor cell (all lanes active)
            if ((r & 1) == 0) {
                unsigned pk = (unsigned)f2bf(w) | ((unsigned)f2bf(nb) << 16);
                *(unsigned*)&lds_w[wv][tok][ct * 16 + r] = pk;
            }
        }
    }
    __syncthreads();

    // ---- Phase 5: blended = W @ proto  via protoT B-frags ----
    bf16x8 aw[8];
    #pragma unroll
    for (int ks = 0; ks < 8; ++ks)
        aw[ks] = *(const bf16x8*)&lds_w[wv][r][ks * 32 + k8];

    float* bout = out_blend + (size_t)tb * DIM;
    for (int dt = 0; dt < 32; dt += 2) {
        f32x4 acc0 = {0.f, 0.f, 0.f, 0.f};
        f32x4 acc1 = {0.f, 0.f, 0.f, 0.f};
        const unsigned short* b0 = protoT + (size_t)((dt + 0) * 16 + r) * NCELLS + k8;
        const unsigned short* b1 = protoT + (size_t)((dt + 1) * 16 + r) * NCELLS + k8;
        #pragma unroll
        for (int ks = 0; ks < 8; ++ks) {
            bf16x8 v0 = *(const bf16x8*)(b0 + ks * 32);
            bf16x8 v1 = *(const bf16x8*)(b1 + ks * 32);
            acc0 = __builtin_amdgcn_mfma_f32_16x16x32_bf16(aw[ks], v0, acc0, 0, 0, 0);
            acc1 = __builtin_amdgcn_mfma_f32_16x16x32_bf16(aw[ks], v1, acc1, 0, 0, 0);
        }
        #pragma unroll
        for (int j = 0; j < 4; ++j) {
            bout[(size_t)(g * 4 + j) * DIM + (dt + 0) * 16 + r] = acc0[j];
            bout[(size_t)(g * 4 + j) * DIM + (dt + 1) * 16 + r] = acc1[j];
        }
    }
}

// ---------------- launch ----------------
extern "C" void kernel_launch(void* const* d_in, const int* in_sizes, int n_in,
                              void* d_out, int out_size, void* d_ws, size_t ws_size,
                              hipStream_t stream) {
    const float* x           = (const float*)d_in[0];
    const float* proto       = (const float*)d_in[1];
    const float* grid        = (const float*)d_in[2];
    const float* temp_raw    = (const float*)d_in[3];
    const float* gate_logits = (const float*)d_in[4];

    float* out       = (float*)d_out;
    float* out_blend = out;                          // [N][512]
    float* out_w     = out + (size_t)NTOK * DIM;     // [N][256]

    char* ws = (char*)d_ws;
    unsigned short* pcomb  = (unsigned short*)(ws);            // 524288 B
    unsigned short* protoT = (unsigned short*)(ws + 524288);   // 262144 B
    float* pp   = (float*)(ws + 786432);
    float* gg   = (float*)(ws + 787456);
    float* gate = (float*)(ws + 788480);
    float* invT = (float*)(ws + 789504);
    // needs ~790 KB of workspace

    prep_kernel<<<dim3(NCELLS), dim3(256), 0, stream>>>(
        proto, grid, temp_raw, gate_logits, pcomb, protoT, pp, gg, gate, invT);
    som_main<<<dim3(NTOK / 64), dim3(256), 0, stream>>>(
        x, pcomb, protoT, pp, gg, gate, invT, out_blend, out_w);
}

// Round 2
// 339.470 us; speedup vs baseline: 2.4289x; 2.4289x over previous
//
#include <hip/hip_runtime.h>
#include <hip/hip_bf16.h>

#define NCELLS 256
#define DIM    512
#define NTOK   131072

typedef __attribute__((ext_vector_type(8))) short  bf16x8;
typedef __attribute__((ext_vector_type(4))) float  f32x4;

static __device__ __forceinline__ unsigned short f2bf(float f) {
    union { float f; unsigned u; } v; v.f = f;
    unsigned r = v.u + 0x7fffu + ((v.u >> 16) & 1u);
    return (unsigned short)(r >> 16);
}

static __device__ __forceinline__ bf16x8 cvt8(f32x4 a, f32x4 b) {
    bf16x8 r;
    r[0] = (short)f2bf(a[0]); r[1] = (short)f2bf(a[1]);
    r[2] = (short)f2bf(a[2]); r[3] = (short)f2bf(a[3]);
    r[4] = (short)f2bf(b[0]); r[5] = (short)f2bf(b[1]);
    r[6] = (short)f2bf(b[2]); r[7] = (short)f2bf(b[3]);
    return r;
}

// async copy of a 16 KB chunk (8192 ushorts) global->LDS, 256 threads
// LDS dest is linear: slot = i*256 + tid -> wave-uniform base + lane*16  (rule #21 safe)
static __device__ __forceinline__ void stage16k(const unsigned short* __restrict__ g,
                                                unsigned short* l, int tid) {
    #pragma unroll
    for (int i = 0; i < 4; ++i) {
        const int slot = i * 256 + tid;
        __builtin_amdgcn_global_load_lds(
            (const __attribute__((address_space(1))) unsigned int*)(g + slot * 8),
            (__attribute__((address_space(3))) unsigned int*)(l + slot * 8),
            16, 0, 0);
    }
}

// ---------------- prep: pre-swizzled bf16 layouts + norms + gate + 1/T ----------------
// pcombL: 32 chunks of [16 rows][512 dims]; chunk 2*ct = proto cells ct*16..+15,
//         chunk 2*ct+1 = grid cells ct*16..+15. Within a row, 16B unit kb is stored
//         at unit (kb ^ (row&7))  -> conflict-free ds_read_b128 B-fragments.
// protoTL: 16 chunks of [32 dim-rows][256 cells]; unit cb stored at (cb ^ (dimrow&7)).
__global__ void __launch_bounds__(256) prep_kernel(
        const float* __restrict__ proto, const float* __restrict__ grid,
        const float* __restrict__ temp_raw, const float* __restrict__ gate_logits,
        unsigned short* __restrict__ pcombL,
        unsigned short* __restrict__ protoTL,
        float* __restrict__ pp, float* __restrict__ gg,
        float* __restrict__ gate, float* __restrict__ invT)
{
    const int c = blockIdx.x;   // cell 0..255
    const int t = threadIdx.x;  // 0..255
    const int rl = c & 15, ct = c >> 4;
    float sp = 0.f, sg = 0.f;
    for (int i = t; i < DIM; i += 256) {
        float pv = proto[c * DIM + i];
        float gv = grid[c * DIM + i];
        const int kb = i >> 3, e = i & 7;
        const int sw = ((kb ^ (rl & 7)) << 3) + e;
        pcombL[(2 * ct) * 8192 + rl * 512 + sw]     = f2bf(pv);
        pcombL[(2 * ct + 1) * 8192 + rl * 512 + sw] = f2bf(gv);
        const int dt2 = i >> 5, dl = i & 31, cb = c >> 3, ce = c & 7;
        protoTL[dt2 * 8192 + dl * 256 + ((cb ^ (dl & 7)) << 3) + ce] = f2bf(pv);
        sp += pv * pv; sg += gv * gv;
    }
    for (int m = 1; m < 64; m <<= 1) { sp += __shfl_xor(sp, m); sg += __shfl_xor(sg, m); }
    __shared__ float redp[4], redg[4];
    const int wv = t >> 6;
    if ((t & 63) == 0) { redp[wv] = sp; redg[wv] = sg; }
    __syncthreads();
    if (t == 0) {
        pp[c] = redp[0] + redp[1] + redp[2] + redp[3];
        gg[c] = redg[0] + redg[1] + redg[2] + redg[3];
        gate[c] = 1.f / (1.f + expf(-gate_logits[c]));
        if (c == 0) {
            float T = (1.f / (1.f + expf(-temp_raw[0]))) * (1.f - 0.001f) + 0.001f;
            invT[0] = 1.f / T;
        }
    }
}

// ---------------- main fused kernel ----------------
// 4 waves/block, 16 tokens/wave, 64 tokens/block, 2048 blocks.
// B panels staged in LDS per block (double-buffered, 2-phase pattern).
__global__ void __launch_bounds__(256, 2) som_main(
        const float* __restrict__ x,
        const unsigned short* __restrict__ pcombL,
        const unsigned short* __restrict__ protoTL,
        const float* __restrict__ pp, const float* __restrict__ gg,
        const float* __restrict__ gate, const float* __restrict__ invTp,
        float* __restrict__ out_blend, float* __restrict__ out_w)
{
    const int tid  = threadIdx.x;
    const int lane = tid & 63;
    const int wv   = tid >> 6;
    const int tb   = blockIdx.x * 64 + wv * 16;  // wave's token base
    const int r    = lane & 15;                  // A-row / B-col / C-col index
    const int g    = lane >> 4;                  // lane group 0..3
    const int k8   = g * 8;                      // K sub-offset within 32

    __shared__ __align__(16) unsigned short sbuf[2][8192];     // 2 x 16 KB staging
    __shared__ __align__(16) unsigned short lds_w[4][16][256]; // 32 KB W (XOR-swizzled)

    const float invT = invTp[0];

    // prologue: stage pcombL chunk 0 (hidden under phase 1)
    stage16k(pcombL, sbuf[0], tid);

    // ---- Phase 1: x tile -> A fragments (bf16) + |x|^2 (fp32) ----
    bf16x8 a1[16];
    float xx_part = 0.f;
    const float* xrow = x + (size_t)(tb + r) * DIM;
    #pragma unroll
    for (int ks = 0; ks < 16; ++ks) {
        const f32x4* p0 = (const f32x4*)(xrow + ks * 32 + k8);
        f32x4 u0 = p0[0], u1 = p0[1];
        #pragma unroll
        for (int i = 0; i < 4; ++i) xx_part += u0[i] * u0[i] + u1[i] * u1[i];
        a1[ks] = cvt8(u0, u1);
    }
    xx_part += __shfl_xor(xx_part, 16);
    xx_part += __shfl_xor(xx_part, 32);
    float xt[4];
    #pragma unroll
    for (int j = 0; j < 4; ++j) xt[j] = __shfl(xx_part, g * 4 + j);

    // preload per-cell constants (cell = ct*16 + r)
    float ppr[16], ggr[16], gtr[16];
    #pragma unroll
    for (int ct = 0; ct < 16; ++ct) {
        ppr[ct] = pp[ct * 16 + r];
        ggr[ct] = gg[ct * 16 + r];
        gtr[ct] = gate[ct * 16 + r];
    }

    __syncthreads();  // chunk 0 staged

    // ---- Phase 2: 32 chunks (alternating P,G rows of 16 cells) ----
    f32x4 zfr[16];
    f32x4 accP = {0.f, 0.f, 0.f, 0.f};
    float m4[4] = {-1e30f, -1e30f, -1e30f, -1e30f};
    for (int c2 = 0; c2 < 32; ++c2) {
        if (c2 < 31) stage16k(pcombL + (c2 + 1) * 8192, sbuf[(c2 + 1) & 1], tid);
        const unsigned short* bb = sbuf[c2 & 1];
        f32x4 aA = {0.f, 0.f, 0.f, 0.f};
        f32x4 aB = {0.f, 0.f, 0.f, 0.f};
        #pragma unroll
        for (int ks = 0; ks < 8; ++ks) {
            bf16x8 b0 = *(const bf16x8*)(bb + r * 512 + (((ks * 4 + g) ^ (r & 7)) << 3));
            bf16x8 b1 = *(const bf16x8*)(bb + r * 512 + ((((ks + 8) * 4 + g) ^ (r & 7)) << 3));
            aA = __builtin_amdgcn_mfma_f32_16x16x32_bf16(a1[ks], b0, aA, 0, 0, 0);
            aB = __builtin_amdgcn_mfma_f32_16x16x32_bf16(a1[ks + 8], b1, aB, 0, 0, 0);
        }
        aA = aA + aB;
        if (!(c2 & 1)) {
            accP = aA;
        } else {
            const int ct = c2 >> 1;
            const float ppc = ppr[ct], ggc = ggr[ct];
            f32x4 z;
            #pragma unroll
            for (int j = 0; j < 4; ++j) {
                float dp = sqrtf(fmaxf(xt[j] + ppc - 2.f * accP[j], 0.f));
                float dg = sqrtf(fmaxf(xt[j] + ggc - 2.f * aA[j], 0.f));
                z[j] = -(dp + dg) * invT;
                m4[j] = fmaxf(m4[j], z[j]);
            }
            zfr[ct] = z;
        }
        __syncthreads();
    }

    // prologue for phase 5 (hidden under softmax + W write)
    stage16k(protoTL, sbuf[0], tid);

    // ---- Phase 3: softmax over 256 cells (cross-lane within 16-lane group) ----
    #pragma unroll
    for (int j = 0; j < 4; ++j) {
        float m = m4[j];
        m = fmaxf(m, __shfl_xor(m, 1));
        m = fmaxf(m, __shfl_xor(m, 2));
        m = fmaxf(m, __shfl_xor(m, 4));
        m = fmaxf(m, __shfl_xor(m, 8));
        m4[j] = m;
    }
    float s1[4] = {0.f, 0.f, 0.f, 0.f};
    float s2[4] = {0.f, 0.f, 0.f, 0.f};
    #pragma unroll
    for (int ct = 0; ct < 16; ++ct) {
        f32x4 z = zfr[ct];
        #pragma unroll
        for (int j = 0; j < 4; ++j) {
            float p = __expf(z[j] - m4[j]);
            s1[j] += p;
            float q = p * gtr[ct];
            s2[j] += q;
            z[j] = q;
        }
        zfr[ct] = z;
    }
    float rden[4];
    #pragma unroll
    for (int j = 0; j < 4; ++j) {
        float a = s1[j], b = s2[j];
        a += __shfl_xor(a, 1); b += __shfl_xor(b, 1);
        a += __shfl_xor(a, 2); b += __shfl_xor(b, 2);
        a += __shfl_xor(a, 4); b += __shfl_xor(b, 4);
        a += __shfl_xor(a, 8); b += __shfl_xor(b, 8);
        rden[j] = 1.f / (b + 1e-8f * a);
    }

    // ---- Phase 4: write weights (fp32) + stash bf16 W into LDS (swizzled) ----
    float* wout = out_w + (size_t)tb * NCELLS;
    #pragma unroll
    for (int ct = 0; ct < 16; ++ct) {
        #pragma unroll
        for (int j = 0; j < 4; ++j) {
            float w = zfr[ct][j] * rden[j];
            const int tok = g * 4 + j;
            wout[(size_t)tok * NCELLS + ct * 16 + r] = w;
            float nb = __shfl_xor(w, 1);  // neighbor cell (all lanes active)
            if ((r & 1) == 0) {
                unsigned pk = (unsigned)f2bf(w) | ((unsigned)f2bf(nb) << 16);
                const int kbw = ct * 2 + (r >> 3);           // 16B unit of cell index
                const int si = ((kbw ^ (tok & 7)) << 3) + (r & 7);
                *(unsigned*)&lds_w[wv][tok][si] = pk;
            }
        }
    }
    __syncthreads();  // W visible + protoTL chunk 0 staged

    // ---- Phase 5: blended = W @ proto, 16 chunks of 32 dim-rows ----
    bf16x8 aw[8];
    #pragma unroll
    for (int ks = 0; ks < 8; ++ks)
        aw[ks] = *(const bf16x8*)&lds_w[wv][r][((ks * 4 + g) ^ (r & 7)) << 3];

    float* bout = out_blend + (size_t)tb * DIM;
    for (int d2 = 0; d2 < 16; ++d2) {
        if (d2 < 15) stage16k(protoTL + (d2 + 1) * 8192, sbuf[(d2 + 1) & 1], tid);
        const unsigned short* bb = sbuf[d2 & 1];
        f32x4 acc0 = {0.f, 0.f, 0.f, 0.f};
        f32x4 acc1 = {0.f, 0.f, 0.f, 0.f};
        #pragma unroll
        for (int ks = 0; ks < 8; ++ks) {
            bf16x8 b0 = *(const bf16x8*)(bb + r * 256 + (((ks * 4 + g) ^ (r & 7)) << 3));
            bf16x8 b1 = *(const bf16x8*)(bb + (16 + r) * 256 + (((ks * 4 + g) ^ ((16 + r) & 7)) << 3));
            acc0 = __builtin_amdgcn_mfma_f32_16x16x32_bf16(aw[ks], b0, acc0, 0, 0, 0);
            acc1 = __builtin_amdgcn_mfma_f32_16x16x32_bf16(aw[ks], b1, acc1, 0, 0, 0);
        }
        #pragma unroll
        for (int j = 0; j < 4; ++j) {
            bout[(size_t)(g * 4 + j) * DIM + d2 * 32 + r]      = acc0[j];
            bout[(size_t)(g * 4 + j) * DIM + d2 * 32 + 16 + r] = acc1[j];
        }
        __syncthreads();
    }
}

// ---------------- launch ----------------
extern "C" void kernel_launch(void* const* d_in, const int* in_sizes, int n_in,
                              void* d_out, int out_size, void* d_ws, size_t ws_size,
                              hipStream_t stream) {
    const float* x           = (const float*)d_in[0];
    const float* proto       = (const float*)d_in[1];
    const float* grid        = (const float*)d_in[2];
    const float* temp_raw    = (const float*)d_in[3];
    const float* gate_logits = (const float*)d_in[4];

    float* out       = (float*)d_out;
    float* out_blend = out;                          // [N][512]
    float* out_w     = out + (size_t)NTOK * DIM;     // [N][256]

    char* ws = (char*)d_ws;
    unsigned short* pcombL  = (unsigned short*)(ws);            // 524288 B
    unsigned short* protoTL = (unsigned short*)(ws + 524288);   // 262144 B
    float* pp   = (float*)(ws + 786432);
    float* gg   = (float*)(ws + 787456);
    float* gate = (float*)(ws + 788480);
    float* invT = (float*)(ws + 789504);

    prep_kernel<<<dim3(NCELLS), dim3(256), 0, stream>>>(
        proto, grid, temp_raw, gate_logits, pcombL, protoTL, pp, gg, gate, invT);
    som_main<<<dim3(NTOK / 64), dim3(256), 0, stream>>>(
        x, pcombL, protoTL, pp, gg, gate, invT, out_blend, out_w);
}